// Round 13
// baseline (98.004 us; speedup 1.0000x reference)
//
#include <hip/hip_runtime.h>
#include <stdint.h>

#define B_ 8
#define N_ 4096
#define D_ 512
#define INV_T 0.04419417382415922f  // 1/sqrt(512)

typedef unsigned short u16;
typedef float f32x4 __attribute__((ext_vector_type(4)));
typedef __bf16 bf16x8 __attribute__((ext_vector_type(8)));
typedef unsigned short u16x8 __attribute__((ext_vector_type(8)));

__device__ __forceinline__ u16 f2bf(float x) {
  union { float f; uint32_t u; } c;
  c.f = x;
  uint32_t r = c.u + 0x7FFFu + ((c.u >> 16) & 1u);
  return (u16)(r >> 16);
}

__device__ __forceinline__ void load_lds16(const u16* g, u16* l) {
  __builtin_amdgcn_global_load_lds(
      (__attribute__((address_space(1))) void*)(g),
      (__attribute__((address_space(3))) void*)(l), 16, 0, 0);
}

// Fused transpose+gemm1, WAVE-PRIVATE staging, ZERO barriers.
// Sp[kz*8+b][d][e] = sum_{n in slice} k[b][n][d]*v[b][n][e], split-K=4.
// Each wave owns a 64x64 output tile and stages its own A/B halves
// (4KB+4KB, dbuf) in private LDS -> no cross-wave sync; 8 independent
// waves/CU hide each other's latencies. Swizzle idx^=((d&7)<<3): same
// bijection on write & read (rule #21), bank-floor for b128 both ways.
__global__ __launch_bounds__(256) void k_gemm1w(const float* __restrict__ kin,
                                                const float* __restrict__ vin,
                                                float* __restrict__ Sp) {
  __shared__ u16 lds[4][2][2][64 * 32];  // [wave][buf][A|B][64d x 32n] = 64 KB
  const int flat = blockIdx.x;  // 0..511, XCD-swizzled
  const int swz = (flat & 7) * 64 + (flat >> 3);
  const int z = swz >> 4;                      // 0..31
  const int bm = (swz >> 2) & 3, bn = swz & 3;
  const int b = z & 7, kz = z >> 3;            // split-K = 4, 1024 n per slice
  const int tid = threadIdx.x;
  const int wave = tid >> 6, lane = tid & 63;
  const int wr = wave >> 1, wc = wave & 1;
  const int lrow = lane & 15, lk = (lane >> 4) * 8;
  const int cq = lane & 15;   // d-chunk (4 cols) within the wave's 64
  const int gq = lane >> 4;   // n-group (8 rows) within the 32-row step
  const float* ga = kin + (size_t)b * N_ * D_ +
                    (size_t)(kz * 1024 + 8 * gq) * D_ + bm * 128 + wr * 64 + 4 * cq;
  const float* gb = vin + (size_t)b * N_ * D_ +
                    (size_t)(kz * 1024 + 8 * gq) * D_ + bn * 128 + wc * 64 + 4 * cq;
  float* C = Sp + (size_t)z * ((size_t)D_ * D_);
  u16* A0 = &lds[wave][0][0][0];
  u16* B0 = &lds[wave][0][1][0];
  u16* A1 = &lds[wave][1][0][0];
  u16* B1 = &lds[wave][1][1][0];

  const f32x4 fzero = {0.f, 0.f, 0.f, 0.f};
  f32x4 acc[4][4];
#pragma unroll
  for (int m = 0; m < 4; ++m)
#pragma unroll
    for (int n = 0; n < 4; ++n) acc[m][n] = fzero;

  f32x4 sA[8], sB[8];  // one prefetch set (fully unrolled -> static indices)

#define LOADSET(STEP)                                                      \
  {                                                                        \
    _Pragma("unroll") for (int j = 0; j < 8; ++j) {                        \
      sA[j] = *(const f32x4*)(ga + (size_t)((STEP)*32 + j) * D_);          \
      sB[j] = *(const f32x4*)(gb + (size_t)((STEP)*32 + j) * D_);          \
    }                                                                      \
  }
  // transpose 8(n) x 4(d) per thread -> 4 d-rows of bf16x8, one b128 each
#define CVTW(AP, BP)                                                       \
  {                                                                        \
    _Pragma("unroll") for (int i = 0; i < 4; ++i) {                        \
      bf16x8 wa, wb;                                                       \
      _Pragma("unroll") for (int j = 0; j < 8; ++j) {                      \
        wa[j] = (__bf16)sA[j][i];                                          \
        wb[j] = (__bf16)sB[j][i];                                          \
      }                                                                    \
      const int d = 4 * cq + i;                                            \
      const int sidx = (d * 32 + 8 * gq) ^ ((d & 7) << 3);                 \
      *(bf16x8*)(AP + sidx) = wa;                                          \
      *(bf16x8*)(BP + sidx) = wb;                                          \
    }                                                                      \
  }
#define STEP_FULL(APc, BPc, APn, BPn, DO_C, STEPL, DO_L)                   \
  {                                                                        \
    bf16x8 af[4], bfv[4];                                                  \
    _Pragma("unroll") for (int m = 0; m < 4; ++m) {                        \
      const int row = m * 16 + lrow;                                       \
      const int ix = (row * 32 + lk) ^ ((row & 7) << 3);                   \
      af[m] = *(const bf16x8*)(APc + ix);                                  \
      bfv[m] = *(const bf16x8*)(BPc + ix);                                 \
    }                                                                      \
    if (DO_C) CVTW(APn, BPn)                                               \
    if (DO_L) LOADSET(STEPL)                                               \
    _Pragma("unroll") for (int m = 0; m < 4; ++m)                          \
      _Pragma("unroll") for (int n = 0; n < 4; ++n)                        \
        acc[m][n] = __builtin_amdgcn_mfma_f32_16x16x32_bf16(               \
            af[m], bfv[n], acc[m][n], 0, 0, 0);                            \
  }

  // prologue: step0 -> buf0; step1 staged in regs
  LOADSET(0)
  CVTW(A0, B0)
  LOADSET(1)

  for (int m2 = 0; m2 < 16; ++m2) {
    const int t = 2 * m2;
    // even step t: consume buf0; cvt step t+1 -> buf1; load step t+2
    STEP_FULL(A0, B0, A1, B1, true, t + 2, t + 2 < 32)
    // odd step t+1: consume buf1; cvt step t+2 -> buf0; load step t+3
    STEP_FULL(A1, B1, A0, B0, t + 2 < 32, t + 3, t + 3 < 32)
  }
#undef LOADSET
#undef CVTW
#undef STEP_FULL

  // C/D layout (m89-verified): row = (lane>>4)*4 + reg, col = lane&15
  const int crow = (lane >> 4) * 4, ccol = lane & 15;
#pragma unroll
  for (int m = 0; m < 4; ++m) {
    const int grow = bm * 128 + wr * 64 + m * 16 + crow;
#pragma unroll
    for (int n = 0; n < 4; ++n) {
      const int gcol = bn * 128 + wc * 64 + n * 16 + ccol;
#pragma unroll
      for (int i2 = 0; i2 < 4; ++i2)
        C[(size_t)(grow + i2) * D_ + gcol] = acc[m][n][i2];
    }
  }
}

// Sum 4 split-K partials, scale by 1/T, softmax rows, write attn fp32.
__global__ __launch_bounds__(256) void k_softmax(const float* __restrict__ Sp,
                                                 float* __restrict__ attn) {
  const int t = threadIdx.x;
  const int wave = t >> 6, lane = t & 63;
  const int g = blockIdx.x * 4 + wave;  // 0..4095 rows
  const int b = g >> 9, d = g & 511;
  const float* base = Sp + (size_t)b * (D_ * D_) + (size_t)d * D_ + lane * 8;
  float s[8];
#pragma unroll
  for (int jj = 0; jj < 8; ++jj) s[jj] = 0.f;
#pragma unroll
  for (int kz = 0; kz < 4; ++kz) {
    const f32x4 p0 = *(const f32x4*)(base + (size_t)kz * 8 * (D_ * D_));
    const f32x4 p1 = *(const f32x4*)(base + (size_t)kz * 8 * (D_ * D_) + 4);
#pragma unroll
    for (int jj = 0; jj < 4; ++jj) { s[jj] += p0[jj]; s[4 + jj] += p1[jj]; }
  }
#pragma unroll
  for (int jj = 0; jj < 8; ++jj) s[jj] *= INV_T;  // temperature
  float mx = s[0];
#pragma unroll
  for (int jj = 1; jj < 8; ++jj) mx = fmaxf(mx, s[jj]);
  for (int o = 32; o > 0; o >>= 1) mx = fmaxf(mx, __shfl_xor(mx, o));
  float sum = 0.f;
#pragma unroll
  for (int jj = 0; jj < 8; ++jj) { s[jj] = __expf(s[jj] - mx); sum += s[jj]; }
  for (int o = 32; o > 0; o >>= 1) sum += __shfl_xor(sum, o);
  const float inv = 1.0f / sum;
  float* orow = attn + (size_t)b * (D_ * D_) + (size_t)d * D_ + lane * 8;
  f32x4 o0, o1;
#pragma unroll
  for (int jj = 0; jj < 4; ++jj) { o0[jj] = s[jj] * inv; o1[jj] = s[4 + jj] * inv; }
  *(f32x4*)orow = o0;
  *(f32x4*)(orow + 4) = o1;
}

// attn fp32 [b][d][e] -> attnT bf16 [b][e][d]
__global__ __launch_bounds__(256) void k_attn_t(const float* __restrict__ attn,
                                                u16* __restrict__ attnT) {
  __shared__ float lds[64][65];
  const int t = threadIdx.x;
  const int b = blockIdx.z;
  const float* src = attn + (size_t)b * D_ * D_;
  u16* dst = attnT + (size_t)b * D_ * D_;
  const int d0 = blockIdx.x * 64, e0 = blockIdx.y * 64;
#pragma unroll
  for (int i = 0; i < 4; ++i) {
    const int fidx = i * 256 + t;
    const int r = fidx >> 4, c4 = fidx & 15;
    const f32x4 f = *(const f32x4*)(src + (size_t)(d0 + r) * D_ + e0 + c4 * 4);
#pragma unroll
    for (int jj = 0; jj < 4; ++jj) lds[r][c4 * 4 + jj] = f[jj];
  }
  __syncthreads();
#pragma unroll
  for (int j = 0; j < 2; ++j) {
    const int sidx = j * 256 + t;
    const int rd = sidx >> 3, c8 = sidx & 7;
    u16x8 o;
#pragma unroll
    for (int jj = 0; jj < 8; ++jj) o[jj] = f2bf(lds[c8 * 8 + jj][rd]);
    *(u16x8*)(dst + (size_t)(e0 + rd) * D_ + d0 + c8 * 8) = o;
  }
}

// gemm2: out[b][n][e] = sum_d v[b][n][d] * attnT[b][e][d]
// Double-buffered LDS, one barrier per step (r6-proven version).
__global__ __launch_bounds__(256) void k_gemm2(const float* __restrict__ v,
                                               const u16* __restrict__ attnT,
                                               float* __restrict__ out) {
  __shared__ u16 As[2][128 * 32];
  __shared__ u16 Bs[2][128 * 32];
  const int bm = blockIdx.x, bn = blockIdx.y, b = blockIdx.z;
  const float* Ab = v + (size_t)b * ((size_t)N_ * D_) + (size_t)(bm * 128) * D_;
  const u16* Bb = attnT + (size_t)b * ((size_t)D_ * D_) + (size_t)(bn * 128) * D_;
  float* C = out + (size_t)b * ((size_t)N_ * D_);
  const int tid = threadIdx.x;
  const int wave = tid >> 6, lane = tid & 63;
  const int wr = wave >> 1, wc = wave & 1;
  const int lrow = lane & 15, lk = (lane >> 4) * 8;
  const int srow = lane >> 2, scol = (lane & 3) * 8;
  const int arow0 = tid >> 2, ac8 = tid & 3;  // A-staging: 4 threads/row
  const f32x4 fzero = {0.f, 0.f, 0.f, 0.f};
  f32x4 acc[4][4];
#pragma unroll
  for (int m = 0; m < 4; ++m)
#pragma unroll
    for (int n = 0; n < 4; ++n) acc[m][n] = fzero;

  f32x4 rf0[2], rf1[2];
#pragma unroll
  for (int i = 0; i < 2; ++i) {
    const int row = i * 64 + arow0;
    rf0[i] = *(const f32x4*)(Ab + (size_t)row * D_ + ac8 * 8);
    rf1[i] = *(const f32x4*)(Ab + (size_t)row * D_ + ac8 * 8 + 4);
  }

  for (int kt = 0; kt < 16; ++kt) {
    const int k0 = kt * 32;
    u16* Ad = As[kt & 1];
    u16* Bd = Bs[kt & 1];
#pragma unroll
    for (int i = 0; i < 2; ++i) {
      const int cc = i * 4 + wave;
      load_lds16(Bb + (size_t)(cc * 16 + srow) * D_ + k0 + scol, Bd + cc * 512);
    }
#pragma unroll
    for (int i = 0; i < 2; ++i) {
      const int row = i * 64 + arow0;
      bf16x8 o;
#pragma unroll
      for (int jj = 0; jj < 4; ++jj) {
        o[jj] = (__bf16)rf0[i][jj];
        o[4 + jj] = (__bf16)rf1[i][jj];
      }
      *(bf16x8*)(Ad + row * 32 + ac8 * 8) = o;
    }
    if (kt + 1 < 16) {
#pragma unroll
      for (int i = 0; i < 2; ++i) {
        const int row = i * 64 + arow0;
        rf0[i] = *(const f32x4*)(Ab + (size_t)row * D_ + (k0 + 32) + ac8 * 8);
        rf1[i] = *(const f32x4*)(Ab + (size_t)row * D_ + (k0 + 32) + ac8 * 8 + 4);
      }
    }
    __syncthreads();
    bf16x8 af[4], bfv[4];
#pragma unroll
    for (int m = 0; m < 4; ++m)
      af[m] = *(const bf16x8*)(Ad + (wr * 64 + m * 16 + lrow) * 32 + lk);
#pragma unroll
    for (int n = 0; n < 4; ++n)
      bfv[n] = *(const bf16x8*)(Bd + (wc * 64 + n * 16 + lrow) * 32 + lk);
#pragma unroll
    for (int m = 0; m < 4; ++m)
#pragma unroll
      for (int n = 0; n < 4; ++n)
        acc[m][n] = __builtin_amdgcn_mfma_f32_16x16x32_bf16(af[m], bfv[n],
                                                            acc[m][n], 0, 0, 0);
  }
  const int crow = (lane >> 4) * 4, ccol = lane & 15;
#pragma unroll
  for (int m = 0; m < 4; ++m) {
    const int grow = bm * 128 + wr * 64 + m * 16 + crow;
#pragma unroll
    for (int n = 0; n < 4; ++n) {
      const int gcol = bn * 128 + wc * 64 + n * 16 + ccol;
#pragma unroll
      for (int i2 = 0; i2 < 4; ++i2)
        C[(size_t)(grow + i2) * D_ + gcol] = acc[m][n][i2];
    }
  }
}

extern "C" void kernel_launch(void* const* d_in, const int* in_sizes, int n_in,
                              void* d_out, int out_size, void* d_ws, size_t ws_size,
                              hipStream_t stream) {
  const float* v = (const float*)d_in[0];
  const float* k = (const float*)d_in[1];
  float* out = (float*)d_out;                        // [8][4096][512] fp32, 64 MiB
  float* attn = out + (size_t)B_ * N_ * D_;          // [8][512][512] fp32, 8 MiB
  // Split-K partials: 4 x [8][512][512] f32 = 32 MiB in the out region
  // (dead until gemm2 overwrites it).
  float* Sp = (float*)d_out;
  u16* attnT = (u16*)d_ws;                           // [8][512][512] bf16, 4 MiB

  k_gemm1w<<<dim3(512), dim3(256), 0, stream>>>(k, v, Sp);
  k_softmax<<<dim3(1024), dim3(256), 0, stream>>>(Sp, attn);
  k_attn_t<<<dim3(8, 8, 8), dim3(256), 0, stream>>>(attn, attnT);
  k_gemm2<<<dim3(32, 4, 8), dim3(256), 0, stream>>>(v, attnT, out);
}

// Round 14
// 91.716 us; speedup vs baseline: 1.0686x; 1.0686x over previous
//
#include <hip/hip_runtime.h>
#include <stdint.h>

#define B_ 8
#define N_ 4096
#define D_ 512
#define INV_T 0.04419417382415922f  // 1/sqrt(512)

typedef unsigned short u16;
typedef float f32x2 __attribute__((ext_vector_type(2)));
typedef float f32x4 __attribute__((ext_vector_type(4)));
typedef __bf16 bf16x8 __attribute__((ext_vector_type(8)));
typedef unsigned short u16x8 __attribute__((ext_vector_type(8)));

__device__ __forceinline__ u16 f2bf(float x) {
  union { float f; uint32_t u; } c;
  c.f = x;
  uint32_t r = c.u + 0x7FFFu + ((c.u >> 16) & 1u);
  return (u16)(r >> 16);
}

__device__ __forceinline__ void load_lds16(const u16* g, u16* l) {
  __builtin_amdgcn_global_load_lds(
      (__attribute__((address_space(1))) void*)(g),
      (__attribute__((address_space(3))) void*)(l), 16, 0, 0);
}

__device__ __forceinline__ void barrier_lgkm_only() {
  asm volatile("s_waitcnt lgkmcnt(0)" ::: "memory");
  __builtin_amdgcn_sched_barrier(0);
  __builtin_amdgcn_s_barrier();
  __builtin_amdgcn_sched_barrier(0);
}

// Fused transpose+gemm1, 256x256 tile, split-K=8 (512 n/slice), 512 threads.
// Sp[kz*8+b][d][e] = sum_n k[b][n][d]*v[b][n][e].  16 K-steps (BK=32) vs 32:
// halves the fixed per-step cost AND halves L2/L3 re-read traffic (2x vs 4x).
// Staging: thread owns d-pair x oct cell for A and B; f32x2 coalesced loads;
// b128 LDS writes with slot-XOR swizzle slot^=((row>>1)&3) -- SAME function
// on write and read (rule #21), read side at the b128 bank floor.
__global__ __launch_bounds__(512) void k_gemm1c(const float* __restrict__ kin,
                                                const float* __restrict__ vin,
                                                float* __restrict__ Sp) {
  __shared__ u16 As[2][256 * 32];  // [d][n] 16 KB each, slot-swizzled
  __shared__ u16 Bs[2][256 * 32];
  const int flat = blockIdx.x;  // 0..255, XCD-swizzled
  const int swz = (flat & 7) * 32 + (flat >> 3);
  const int z = swz >> 2;                      // 0..63
  const int tile = swz & 3;
  const int b = z & 7, kz = z >> 3;            // split-K = 8
  const int bm = tile >> 1, bn = tile & 1;     // 2x2 tiles of 256
  const int tid = threadIdx.x;
  const int wave = tid >> 6, lane = tid & 63;
  const int wrow = wave >> 1, wcol = wave & 1;  // wave tile 64x128
  const int lrow = lane & 15, lk = lane >> 4;   // frag row / k-slot (0..3)
  const int dp = tid & 127, oct = tid >> 7;     // staging cell: d=2dp(+1), n-oct
  const float* ga = kin + (size_t)b * N_ * D_ +
                    (size_t)(kz * 512 + oct * 8) * D_ + bm * 256 + 2 * dp;
  const float* gb = vin + (size_t)b * N_ * D_ +
                    (size_t)(kz * 512 + oct * 8) * D_ + bn * 256 + 2 * dp;
  float* C = Sp + (size_t)z * ((size_t)D_ * D_);
  const int wslot = 8 * (oct ^ (dp & 3));  // write slot (d>>1 == dp for both rows)

  f32x4 acc[4][8];
#pragma unroll
  for (int m = 0; m < 4; ++m)
#pragma unroll
    for (int n = 0; n < 8; ++n) acc[m][n] = f32x4{0.f, 0.f, 0.f, 0.f};

  f32x2 rA[8], rB[8];

#define LOADSET(STEP)                                                      \
  {                                                                        \
    _Pragma("unroll") for (int j = 0; j < 8; ++j) {                        \
      rA[j] = *(const f32x2*)(ga + (size_t)((STEP)*32 + j) * D_);          \
      rB[j] = *(const f32x2*)(gb + (size_t)((STEP)*32 + j) * D_);          \
    }                                                                      \
  }
#define CVTW(BUF)                                                          \
  {                                                                        \
    bf16x8 a0, a1, b0, b1;                                                 \
    _Pragma("unroll") for (int j = 0; j < 8; ++j) {                        \
      a0[j] = (__bf16)rA[j][0];                                            \
      a1[j] = (__bf16)rA[j][1];                                            \
      b0[j] = (__bf16)rB[j][0];                                            \
      b1[j] = (__bf16)rB[j][1];                                            \
    }                                                                      \
    *(bf16x8*)(As[BUF] + (2 * dp) * 32 + wslot) = a0;                      \
    *(bf16x8*)(As[BUF] + (2 * dp + 1) * 32 + wslot) = a1;                  \
    *(bf16x8*)(Bs[BUF] + (2 * dp) * 32 + wslot) = b0;                      \
    *(bf16x8*)(Bs[BUF] + (2 * dp + 1) * 32 + wslot) = b1;                  \
  }
#define FRAGS_MFMA(BUF)                                                    \
  {                                                                        \
    bf16x8 af[4], bfv[8];                                                  \
    _Pragma("unroll") for (int m = 0; m < 4; ++m) {                        \
      const int row = wrow * 64 + m * 16 + lrow;                           \
      af[m] = *(const bf16x8*)(As[BUF] + row * 32 +                        \
                               8 * (lk ^ ((row >> 1) & 3)));               \
    }                                                                      \
    _Pragma("unroll") for (int n = 0; n < 8; ++n) {                        \
      const int row = wcol * 128 + n * 16 + lrow;                          \
      bfv[n] = *(const bf16x8*)(Bs[BUF] + row * 32 +                       \
                                8 * (lk ^ ((row >> 1) & 3)));              \
    }                                                                      \
    _Pragma("unroll") for (int m = 0; m < 4; ++m)                          \
      _Pragma("unroll") for (int n = 0; n < 8; ++n)                        \
        acc[m][n] = __builtin_amdgcn_mfma_f32_16x16x32_bf16(               \
            af[m], bfv[n], acc[m][n], 0, 0, 0);                            \
  }

  LOADSET(0)
  for (int kt = 0; kt < 16; ++kt) {
    CVTW(kt & 1)
    if (kt + 1 < 16) LOADSET(kt + 1)
    barrier_lgkm_only();  // buf[kt&1] writes visible; reg loads stay in flight
    FRAGS_MFMA(kt & 1)
    // single barrier: buf[kt&1] rewritten only at kt+2, after barrier kt+1.
  }
#undef LOADSET
#undef CVTW
#undef FRAGS_MFMA

  // C/D layout (m89-verified): row = (lane>>4)*4 + reg, col = lane&15
  const int crow = (lane >> 4) * 4, ccol = lane & 15;
#pragma unroll
  for (int m = 0; m < 4; ++m) {
    const int grow = bm * 256 + wrow * 64 + m * 16 + crow;
#pragma unroll
    for (int n = 0; n < 8; ++n) {
      const int gcol = bn * 256 + wcol * 128 + n * 16 + ccol;
#pragma unroll
      for (int i2 = 0; i2 < 4; ++i2)
        C[(size_t)(grow + i2) * D_ + gcol] = acc[m][n][i2];
    }
  }
}

// Sum 8 split-K partials, scale by 1/T, softmax rows, write attn fp32.
__global__ __launch_bounds__(256) void k_softmax(const float* __restrict__ Sp,
                                                 float* __restrict__ attn) {
  const int t = threadIdx.x;
  const int wave = t >> 6, lane = t & 63;
  const int g = blockIdx.x * 4 + wave;  // 0..4095 rows
  const int b = g >> 9, d = g & 511;
  const float* base = Sp + (size_t)b * (D_ * D_) + (size_t)d * D_ + lane * 8;
  float s[8];
#pragma unroll
  for (int jj = 0; jj < 8; ++jj) s[jj] = 0.f;
#pragma unroll
  for (int kz = 0; kz < 8; ++kz) {
    const f32x4 p0 = *(const f32x4*)(base + (size_t)kz * 8 * (D_ * D_));
    const f32x4 p1 = *(const f32x4*)(base + (size_t)kz * 8 * (D_ * D_) + 4);
#pragma unroll
    for (int jj = 0; jj < 4; ++jj) { s[jj] += p0[jj]; s[4 + jj] += p1[jj]; }
  }
#pragma unroll
  for (int jj = 0; jj < 8; ++jj) s[jj] *= INV_T;  // temperature
  float mx = s[0];
#pragma unroll
  for (int jj = 1; jj < 8; ++jj) mx = fmaxf(mx, s[jj]);
  for (int o = 32; o > 0; o >>= 1) mx = fmaxf(mx, __shfl_xor(mx, o));
  float sum = 0.f;
#pragma unroll
  for (int jj = 0; jj < 8; ++jj) { s[jj] = __expf(s[jj] - mx); sum += s[jj]; }
  for (int o = 32; o > 0; o >>= 1) sum += __shfl_xor(sum, o);
  const float inv = 1.0f / sum;
  float* orow = attn + (size_t)b * (D_ * D_) + (size_t)d * D_ + lane * 8;
  f32x4 o0, o1;
#pragma unroll
  for (int jj = 0; jj < 4; ++jj) { o0[jj] = s[jj] * inv; o1[jj] = s[4 + jj] * inv; }
  *(f32x4*)orow = o0;
  *(f32x4*)(orow + 4) = o1;
}

// attn fp32 [b][d][e] -> attnT bf16 [b][e][d]
__global__ __launch_bounds__(256) void k_attn_t(const float* __restrict__ attn,
                                                u16* __restrict__ attnT) {
  __shared__ float lds[64][65];
  const int t = threadIdx.x;
  const int b = blockIdx.z;
  const float* src = attn + (size_t)b * D_ * D_;
  u16* dst = attnT + (size_t)b * D_ * D_;
  const int d0 = blockIdx.x * 64, e0 = blockIdx.y * 64;
#pragma unroll
  for (int i = 0; i < 4; ++i) {
    const int fidx = i * 256 + t;
    const int r = fidx >> 4, c4 = fidx & 15;
    const f32x4 f = *(const f32x4*)(src + (size_t)(d0 + r) * D_ + e0 + c4 * 4);
#pragma unroll
    for (int jj = 0; jj < 4; ++jj) lds[r][c4 * 4 + jj] = f[jj];
  }
  __syncthreads();
#pragma unroll
  for (int j = 0; j < 2; ++j) {
    const int sidx = j * 256 + t;
    const int rd = sidx >> 3, c8 = sidx & 7;
    u16x8 o;
#pragma unroll
    for (int jj = 0; jj < 8; ++jj) o[jj] = f2bf(lds[c8 * 8 + jj][rd]);
    *(u16x8*)(dst + (size_t)(e0 + rd) * D_ + d0 + c8 * 8) = o;
  }
}

// gemm2: out[b][n][e] = sum_d v[b][n][d] * attnT[b][e][d]
// Double-buffered LDS, one barrier per step (r6-proven version).
__global__ __launch_bounds__(256) void k_gemm2(const float* __restrict__ v,
                                               const u16* __restrict__ attnT,
                                               float* __restrict__ out) {
  __shared__ u16 As2[2][128 * 32];
  __shared__ u16 Bs2[2][128 * 32];
  const int bm = blockIdx.x, bn = blockIdx.y, b = blockIdx.z;
  const float* Ab = v + (size_t)b * ((size_t)N_ * D_) + (size_t)(bm * 128) * D_;
  const u16* Bb = attnT + (size_t)b * ((size_t)D_ * D_) + (size_t)(bn * 128) * D_;
  float* C = out + (size_t)b * ((size_t)N_ * D_);
  const int tid = threadIdx.x;
  const int wave = tid >> 6, lane = tid & 63;
  const int wr = wave >> 1, wc = wave & 1;
  const int lrow = lane & 15, lk = (lane >> 4) * 8;
  const int srow = lane >> 2, scol = (lane & 3) * 8;
  const int arow0 = tid >> 2, ac8 = tid & 3;  // A-staging: 4 threads/row
  f32x4 acc[4][4];
#pragma unroll
  for (int m = 0; m < 4; ++m)
#pragma unroll
    for (int n = 0; n < 4; ++n) acc[m][n] = f32x4{0.f, 0.f, 0.f, 0.f};

  f32x4 rf0[2], rf1[2];
#pragma unroll
  for (int i = 0; i < 2; ++i) {
    const int row = i * 64 + arow0;
    rf0[i] = *(const f32x4*)(Ab + (size_t)row * D_ + ac8 * 8);
    rf1[i] = *(const f32x4*)(Ab + (size_t)row * D_ + ac8 * 8 + 4);
  }

  for (int kt = 0; kt < 16; ++kt) {
    const int k0 = kt * 32;
    u16* Ad = As2[kt & 1];
    u16* Bd = Bs2[kt & 1];
#pragma unroll
    for (int i = 0; i < 2; ++i) {
      const int cc = i * 4 + wave;
      load_lds16(Bb + (size_t)(cc * 16 + srow) * D_ + k0 + scol, Bd + cc * 512);
    }
#pragma unroll
    for (int i = 0; i < 2; ++i) {
      const int row = i * 64 + arow0;
      bf16x8 o;
#pragma unroll
      for (int jj = 0; jj < 4; ++jj) {
        o[jj] = (__bf16)rf0[i][jj];
        o[4 + jj] = (__bf16)rf1[i][jj];
      }
      *(bf16x8*)(Ad + row * 32 + ac8 * 8) = o;
    }
    if (kt + 1 < 16) {
#pragma unroll
      for (int i = 0; i < 2; ++i) {
        const int row = i * 64 + arow0;
        rf0[i] = *(const f32x4*)(Ab + (size_t)row * D_ + (k0 + 32) + ac8 * 8);
        rf1[i] = *(const f32x4*)(Ab + (size_t)row * D_ + (k0 + 32) + ac8 * 8 + 4);
      }
    }
    __syncthreads();
    bf16x8 af[4], bfv[4];
#pragma unroll
    for (int m = 0; m < 4; ++m)
      af[m] = *(const bf16x8*)(Ad + (wr * 64 + m * 16 + lrow) * 32 + lk);
#pragma unroll
    for (int n = 0; n < 4; ++n)
      bfv[n] = *(const bf16x8*)(Bd + (wc * 64 + n * 16 + lrow) * 32 + lk);
#pragma unroll
    for (int m = 0; m < 4; ++m)
#pragma unroll
      for (int n = 0; n < 4; ++n)
        acc[m][n] = __builtin_amdgcn_mfma_f32_16x16x32_bf16(af[m], bfv[n],
                                                            acc[m][n], 0, 0, 0);
  }
  const int crow = (lane >> 4) * 4, ccol = lane & 15;
#pragma unroll
  for (int m = 0; m < 4; ++m) {
    const int grow = bm * 128 + wr * 64 + m * 16 + crow;
#pragma unroll
    for (int n = 0; n < 4; ++n) {
      const int gcol = bn * 128 + wc * 64 + n * 16 + ccol;
#pragma unroll
      for (int i2 = 0; i2 < 4; ++i2)
        C[(size_t)(grow + i2) * D_ + gcol] = acc[m][n][i2];
    }
  }
}

extern "C" void kernel_launch(void* const* d_in, const int* in_sizes, int n_in,
                              void* d_out, int out_size, void* d_ws, size_t ws_size,
                              hipStream_t stream) {
  const float* v = (const float*)d_in[0];
  const float* k = (const float*)d_in[1];
  float* out = (float*)d_out;                        // [8][4096][512] fp32, 64 MiB
  float* attn = out + (size_t)B_ * N_ * D_;          // [8][512][512] fp32, 8 MiB
  // Split-K partials: 8 x [8][512][512] f32 = 64 MiB = the out region
  // (dead until gemm2 overwrites it).
  float* Sp = (float*)d_out;
  u16* attnT = (u16*)d_ws;                           // [8][512][512] bf16, 4 MiB

  k_gemm1c<<<dim3(256), dim3(512), 0, stream>>>(k, v, Sp);
  k_softmax<<<dim3(1024), dim3(256), 0, stream>>>(Sp, attn);
  k_attn_t<<<dim3(8, 8, 8), dim3(256), 0, stream>>>(attn, attnT);
  k_gemm2<<<dim3(32, 4, 8), dim3(256), 0, stream>>>(v, attnT, out);
}